// Round 1
// baseline (1926.067 us; speedup 1.0000x reference)
//
#include <hip/hip_runtime.h>
#include <math.h>

// Problem constants
#define NSEQ 8192          // B*N
#define PATCHL 16
#define HIDN 256
#define VOCABN 256

// ---------------------------------------------------------------------------
// Generic tiled fp32 GEMM:  C[m][n] = sum_k A[m*lda+k]*B[n*ldb+k] (+bias[n])
// i.e. C = A * B^T with both operands K-major (row-major A [M][K], B [N][K]).
// BM=BN=64, BK=16, 256 threads, 4x4 micro-tile per thread.
// All dims assumed divisible (they are: M in {8192,256}, N in {256,768}, K in {1024,256}).
// ---------------------------------------------------------------------------
template<int BM, int BN, int BK>
__global__ __launch_bounds__(256)
void gemm_nt(const float* __restrict__ A, const float* __restrict__ B,
             const float* __restrict__ bias, float* __restrict__ C,
             int K, int lda, int ldb, int ldc)
{
    __shared__ float As[BM][BK + 1];
    __shared__ float Bs[BN][BK + 1];
    const int t  = threadIdx.x;
    const int bm = blockIdx.x * BM;
    const int bn = blockIdx.y * BN;
    const int tx = t & 15, ty = t >> 4;

    float acc[4][4];
#pragma unroll
    for (int i = 0; i < 4; i++)
#pragma unroll
        for (int j = 0; j < 4; j++) acc[i][j] = 0.f;

    const int row = t >> 2;           // 0..63
    const int seg = (t & 3) * 4;      // 0,4,8,12

    for (int k0 = 0; k0 < K; k0 += BK) {
        float4 a4 = *(const float4*)(A + (size_t)(bm + row) * lda + k0 + seg);
        float4 b4 = *(const float4*)(B + (size_t)(bn + row) * ldb + k0 + seg);
        As[row][seg + 0] = a4.x; As[row][seg + 1] = a4.y;
        As[row][seg + 2] = a4.z; As[row][seg + 3] = a4.w;
        Bs[row][seg + 0] = b4.x; Bs[row][seg + 1] = b4.y;
        Bs[row][seg + 2] = b4.z; Bs[row][seg + 3] = b4.w;
        __syncthreads();
#pragma unroll
        for (int kk = 0; kk < BK; kk++) {
            float a[4], b[4];
#pragma unroll
            for (int i = 0; i < 4; i++) a[i] = As[ty * 4 + i][kk];
#pragma unroll
            for (int j = 0; j < 4; j++) b[j] = Bs[tx * 4 + j][kk];
#pragma unroll
            for (int i = 0; i < 4; i++)
#pragma unroll
                for (int j = 0; j < 4; j++) acc[i][j] += a[i] * b[j];
        }
        __syncthreads();
    }

#pragma unroll
    for (int i = 0; i < 4; i++) {
        const int m = bm + ty * 4 + i;
        const int n = bn + tx * 4;
        float4 v;
        v.x = acc[i][0]; v.y = acc[i][1]; v.z = acc[i][2]; v.w = acc[i][3];
        if (bias) { v.x += bias[n]; v.y += bias[n + 1]; v.z += bias[n + 2]; v.w += bias[n + 3]; }
        *(float4*)(C + (size_t)m * ldc + n) = v;
    }
}

// ---------------------------------------------------------------------------
// Fused GRU scan + head.
// Block = 256 threads handles 16 sequences for all 16 steps.
// Thread t owns hidden unit t (and vocab column t for the head).
// h double-buffered in LDS; one barrier per step.
//   latg  [NSEQ][768]  : latent-path input gates incl. b_ih
//   premix[256][768]   : emb_table @ W_ih_emb^T per byte value
// ---------------------------------------------------------------------------
__global__ __launch_bounds__(256)
void gru_head(const int* __restrict__ bytes,       // [NSEQ*16]
              const float* __restrict__ latg,      // [NSEQ][768]
              const float* __restrict__ premix,    // [256][768]
              const float* __restrict__ W_hh,      // [768][256]
              const float* __restrict__ b_hh,      // [768]
              const float* __restrict__ W_head,    // [256][256]
              const float* __restrict__ b_head,    // [256]
              float* __restrict__ out)             // [NSEQ][16][256]
{
    const int t  = threadIdx.x;          // hidden unit / vocab index
    const int s0 = blockIdx.x * 16;      // first sequence of this block

    __shared__ float H[2][16][HIDN];

#pragma unroll
    for (int s = 0; s < 16; s++) H[0][s][t] = 0.f;
    __syncthreads();

    const float* wr = W_hh + (size_t)t * HIDN;
    const float* wz = W_hh + (size_t)(t + 256) * HIDN;
    const float* wn = W_hh + (size_t)(t + 512) * HIDN;
    const float* wh = W_head + (size_t)t * HIDN;
    const float bhr = b_hh[t], bhz = b_hh[t + 256], bhn = b_hh[t + 512];
    const float bhd = b_head[t];

    int cur = 0;
    for (int p = 0; p < PATCHL; p++) {
        // ---- recurrence matvec: hg = h @ W_hh^T (rows t, t+256, t+512) ----
        float accr[16], accz[16], accn[16];
#pragma unroll
        for (int s = 0; s < 16; s++) { accr[s] = 0.f; accz[s] = 0.f; accn[s] = 0.f; }

#pragma unroll 2
        for (int k = 0; k < HIDN; k += 4) {
            const float4 w4r = *(const float4*)(wr + k);
            const float4 w4z = *(const float4*)(wz + k);
            const float4 w4n = *(const float4*)(wn + k);
#pragma unroll
            for (int s = 0; s < 16; s++) {
                const float4 h4 = *(const float4*)(&H[cur][s][k]);
                accr[s] += h4.x * w4r.x + h4.y * w4r.y + h4.z * w4r.z + h4.w * w4r.w;
                accz[s] += h4.x * w4z.x + h4.y * w4z.y + h4.z * w4z.z + h4.w * w4z.w;
                accn[s] += h4.x * w4n.x + h4.y * w4n.y + h4.z * w4n.z + h4.w * w4n.w;
            }
        }

        // ---- gates + state update ----
        float hnew[16];
#pragma unroll
        for (int s = 0; s < 16; s++) {
            const int byte = (p == 0) ? 0 : bytes[(size_t)(s0 + s) * PATCHL + p - 1];
            const float* pm = premix + (size_t)byte * 768;
            const float* lg = latg + (size_t)(s0 + s) * 768;
            const float xr = pm[t]       + lg[t];
            const float xz = pm[t + 256] + lg[t + 256];
            const float xn = pm[t + 512] + lg[t + 512];
            const float r = 1.f / (1.f + __expf(-(xr + accr[s] + bhr)));
            const float z = 1.f / (1.f + __expf(-(xz + accz[s] + bhz)));
            const float n = tanhf(xn + r * (accn[s] + bhn));
            hnew[s] = (1.f - z) * n + z * H[cur][s][t];
        }

        // write new state to the other buffer; single barrier per step
#pragma unroll
        for (int s = 0; s < 16; s++) H[cur ^ 1][s][t] = hnew[s];
        __syncthreads();
        cur ^= 1;

        // ---- head: logits[s][p][t] = h_new[s] . W_head[t] + b_head[t] ----
        float acch[16];
#pragma unroll
        for (int s = 0; s < 16; s++) acch[s] = 0.f;
#pragma unroll 2
        for (int k = 0; k < HIDN; k += 4) {
            const float4 w4 = *(const float4*)(wh + k);
#pragma unroll
            for (int s = 0; s < 16; s++) {
                const float4 h4 = *(const float4*)(&H[cur][s][k]);
                acch[s] += h4.x * w4.x + h4.y * w4.y + h4.z * w4.z + h4.w * w4.w;
            }
        }
#pragma unroll
        for (int s = 0; s < 16; s++)
            out[((size_t)(s0 + s) * PATCHL + p) * VOCABN + t] = acch[s] + bhd;
    }
}

// ---------------------------------------------------------------------------
extern "C" void kernel_launch(void* const* d_in, const int* in_sizes, int n_in,
                              void* d_out, int out_size, void* d_ws, size_t ws_size,
                              hipStream_t stream)
{
    const float* latents = (const float*)d_in[0];   // [8192][1024]
    const int*   tb      = (const int*)d_in[1];     // [8192*16]
    const float* W_proj  = (const float*)d_in[2];   // [256][1024]
    const float* b_proj  = (const float*)d_in[3];   // [256]
    const float* emb     = (const float*)d_in[4];   // [256][256]
    const float* W_ih    = (const float*)d_in[5];   // [768][512]
    const float* W_hh    = (const float*)d_in[6];   // [768][256]
    const float* b_ih    = (const float*)d_in[7];   // [768]
    const float* b_hh    = (const float*)d_in[8];   // [768]
    const float* W_head  = (const float*)d_in[9];   // [256][256]
    const float* b_head  = (const float*)d_in[10];  // [256]
    float* out = (float*)d_out;

    float* ws     = (float*)d_ws;
    float* latg   = ws;                                   // 8192*768
    float* ctx    = ws + (size_t)NSEQ * 768;              // 8192*256
    float* premix = ctx + (size_t)NSEQ * HIDN;            // 256*768

    // ctx = latents @ W_proj^T + b_proj
    hipLaunchKernelGGL((gemm_nt<64, 64, 16>), dim3(NSEQ / 64, 256 / 64), dim3(256), 0, stream,
                       latents, W_proj, b_proj, ctx, 1024, 1024, 1024, 256);
    // latg = ctx @ W_ih[:,256:512]^T + b_ih
    hipLaunchKernelGGL((gemm_nt<64, 64, 16>), dim3(NSEQ / 64, 768 / 64), dim3(256), 0, stream,
                       ctx, W_ih + 256, b_ih, latg, 256, 256, 512, 768);
    // premix = emb_table @ W_ih[:,0:256]^T   (no bias; b_ih folded into latg)
    hipLaunchKernelGGL((gemm_nt<64, 64, 16>), dim3(256 / 64, 768 / 64), dim3(256), 0, stream,
                       emb, W_ih, nullptr, premix, 256, 256, 512, 768);
    // fused GRU scan + head
    hipLaunchKernelGGL(gru_head, dim3(NSEQ / 16), dim3(256), 0, stream,
                       tb, latg, premix, W_hh, b_hh, W_head, b_head, out);
}

// Round 2
// 659.375 us; speedup vs baseline: 2.9211x; 2.9211x over previous
//
#include <hip/hip_runtime.h>
#include <math.h>

// Problem constants
#define NSEQ 8192          // B*N
#define PATCHL 16
#define HIDN 256
#define VOCABN 256

typedef __attribute__((ext_vector_type(4))) float f32x4;
typedef __attribute__((ext_vector_type(8))) short bf16x8;   // 8 bf16 = 4 VGPRs

__device__ __forceinline__ unsigned short f2bf(float f) {
    // round-to-nearest-even fp32 -> bf16
    unsigned int x = __float_as_uint(f);
    unsigned int r = (x + 0x7fffu + ((x >> 16) & 1u)) >> 16;
    return (unsigned short)r;
}
__device__ __forceinline__ float sigf(float x)   { return 1.f / (1.f + __expf(-x)); }
__device__ __forceinline__ float tanhf_(float x) { return 2.f / (1.f + __expf(-2.f * x)) - 1.f; }

// ---------------------------------------------------------------------------
// Tiled fp32 GEMM: C[m][n] = sum_k A[m*lda+k]*B[n*ldb+k] (+bias[n])  (round-1,
// passed). Used for the latent-path pre-projections (kept fp32 for accuracy).
// ---------------------------------------------------------------------------
template<int BM, int BN, int BK>
__global__ __launch_bounds__(256)
void gemm_nt(const float* __restrict__ A, const float* __restrict__ B,
             const float* __restrict__ bias, float* __restrict__ C,
             int K, int lda, int ldb, int ldc)
{
    __shared__ float As[BM][BK + 1];
    __shared__ float Bs[BN][BK + 1];
    const int t  = threadIdx.x;
    const int bm = blockIdx.x * BM;
    const int bn = blockIdx.y * BN;
    const int tx = t & 15, ty = t >> 4;

    float acc[4][4];
#pragma unroll
    for (int i = 0; i < 4; i++)
#pragma unroll
        for (int j = 0; j < 4; j++) acc[i][j] = 0.f;

    const int row = t >> 2;
    const int seg = (t & 3) * 4;

    for (int k0 = 0; k0 < K; k0 += BK) {
        float4 a4 = *(const float4*)(A + (size_t)(bm + row) * lda + k0 + seg);
        float4 b4 = *(const float4*)(B + (size_t)(bn + row) * ldb + k0 + seg);
        As[row][seg + 0] = a4.x; As[row][seg + 1] = a4.y;
        As[row][seg + 2] = a4.z; As[row][seg + 3] = a4.w;
        Bs[row][seg + 0] = b4.x; Bs[row][seg + 1] = b4.y;
        Bs[row][seg + 2] = b4.z; Bs[row][seg + 3] = b4.w;
        __syncthreads();
#pragma unroll
        for (int kk = 0; kk < BK; kk++) {
            float a[4], b[4];
#pragma unroll
            for (int i = 0; i < 4; i++) a[i] = As[ty * 4 + i][kk];
#pragma unroll
            for (int j = 0; j < 4; j++) b[j] = Bs[tx * 4 + j][kk];
#pragma unroll
            for (int i = 0; i < 4; i++)
#pragma unroll
                for (int j = 0; j < 4; j++) acc[i][j] += a[i] * b[j];
        }
        __syncthreads();
    }

#pragma unroll
    for (int i = 0; i < 4; i++) {
        const int m = bm + ty * 4 + i;
        const int n = bn + tx * 4;
        float4 v;
        v.x = acc[i][0]; v.y = acc[i][1]; v.z = acc[i][2]; v.w = acc[i][3];
        if (bias) { v.x += bias[n]; v.y += bias[n + 1]; v.z += bias[n + 2]; v.w += bias[n + 3]; }
        *(float4*)(C + (size_t)m * ldc + n) = v;
    }
}

// ---------------------------------------------------------------------------
// Pack W_hh [768][256] and W_head [256][256] (fp32, row-major) into bf16
// fragment-ordered layout so GRU B-frag loads are coalesced dwordx4:
//   wpack[((T*8 + ks)*64 + lane)*8 + j] =
//       W[T*16 + (lane&15)][ks*32 + ((lane>>4)&3)*8 + j]
// T in [0,48) -> W_hh gate tiles; T in [48,64) -> W_head tiles.
// ---------------------------------------------------------------------------
__global__ __launch_bounds__(256)
void pack_weights(const float* __restrict__ Whh, const float* __restrict__ Whead,
                  unsigned short* __restrict__ wpack)
{
    const int g = blockIdx.x * 256 + threadIdx.x;   // 0..32767
    const int lane = g & 63;
    const int ks = (g >> 6) & 7;
    const int T  = g >> 9;                          // 0..63
    const float* src;
    if (T < 48) src = Whh   + (size_t)(T * 16 + (lane & 15)) * 256;
    else        src = Whead + (size_t)((T - 48) * 16 + (lane & 15)) * 256;
    const int k0 = ks * 32 + ((lane >> 4) & 3) * 8;
    unsigned int q[4];
#pragma unroll
    for (int j = 0; j < 4; j++) {
        unsigned int lo = f2bf(src[k0 + 2 * j]);
        unsigned int hi = f2bf(src[k0 + 2 * j + 1]);
        q[j] = lo | (hi << 16);
    }
    uint4 v; v.x = q[0]; v.y = q[1]; v.z = q[2]; v.w = q[3];
    *(uint4*)(wpack + (size_t)g * 8) = v;
}

// ---------------------------------------------------------------------------
// MFMA GRU scan + head. 256 blocks x 512 threads (8 waves).
// Block owns 32 sequences (2 MFMA M-tiles). Wave w owns hidden/vocab units
// [w*32, w*32+32) => per wave: r/z/n gate tiles {g*16 + w*2 + nt} and head
// tiles {w*2 + nt}. h kept in LDS as bf16 (XOR-swizzled), double-buffered;
// per-lane h also kept in fp32 registers for the z*h_prev path.
// MFMA 16x16x32_bf16 maps (m89/m91): A: lane->(m=l&15, k=(l>>4)*8+j);
// B: lane->(k=(l>>4)*8+j, n=l&15); C/D: lane,reg->(row=(l>>4)*4+reg, col=l&15).
// One barrier per step (buffer-alternation proof in analysis).
// ---------------------------------------------------------------------------
__global__ __launch_bounds__(512)
void gru_head_mfma(const int* __restrict__ bytes,
                   const float* __restrict__ latg,     // [NSEQ][768], incl b_ih
                   const float* __restrict__ premix,   // [256][768]
                   const unsigned short* __restrict__ wpack,
                   const float* __restrict__ b_hh,     // [768]
                   const float* __restrict__ b_head,   // [256]
                   float* __restrict__ out)            // [NSEQ][16][256]
{
    const int tid  = threadIdx.x;
    const int w    = tid >> 6;          // wave 0..7
    const int lane = tid & 63;
    const int l15  = lane & 15;
    const int kg   = (lane >> 4) & 3;
    const int s0   = blockIdx.x * 32;

    __shared__ unsigned short H0[32 * 256];
    __shared__ unsigned short H1[32 * 256];
    __shared__ int BYs[512];            // 32 seqs x 16 bytes

    BYs[tid] = bytes[s0 * PATCHL + tid];
    __syncthreads();

    const unsigned short* wp_hd = wpack + 48 * 8 * 64 * 8;

    float bhr[2], bhz[2], bhn[2], bhd[2];
#pragma unroll
    for (int nt = 0; nt < 2; nt++) {
        const int u = w * 32 + nt * 16 + l15;
        bhr[nt] = b_hh[u]; bhz[nt] = b_hh[256 + u]; bhn[nt] = b_hh[512 + u];
        bhd[nt] = b_head[u];
    }

    float hreg[2][2][4];
#pragma unroll
    for (int mt = 0; mt < 2; mt++)
#pragma unroll
        for (int nt = 0; nt < 2; nt++)
#pragma unroll
            for (int rr = 0; rr < 4; rr++) hreg[mt][nt][rr] = 0.f;

    unsigned short* Hcur = H0;
    unsigned short* Hnxt = H1;

    for (int p = 0; p < PATCHL; ++p) {
        // ---------------- recurrence: hg = h_prev @ W_hh^T ----------------
        f32x4 accr[2][2], accz[2][2], accn[2][2];
#pragma unroll
        for (int mt = 0; mt < 2; mt++)
#pragma unroll
            for (int nt = 0; nt < 2; nt++) {
                accr[mt][nt] = 0.f; accz[mt][nt] = 0.f; accn[mt][nt] = 0.f;
            }
        if (p != 0) {       // h_prev == 0 at p==0
#pragma unroll
            for (int ks = 0; ks < 8; ++ks) {
                bf16x8 a[2];
#pragma unroll
                for (int mt = 0; mt < 2; mt++) {
                    const int s = mt * 16 + l15;
                    const int off = (ks * 64 + kg * 16) ^ ((s & 7) << 4);
                    a[mt] = *(const bf16x8*)(Hcur + s * 256 + (off >> 1));
                }
#pragma unroll
                for (int nt = 0; nt < 2; nt++) {
                    const int tb = w * 2 + nt;
                    const bf16x8 br = *(const bf16x8*)(wpack + (((size_t)(tb)      * 8 + ks) * 64 + lane) * 8);
                    const bf16x8 bz = *(const bf16x8*)(wpack + (((size_t)(16 + tb) * 8 + ks) * 64 + lane) * 8);
                    const bf16x8 bn = *(const bf16x8*)(wpack + (((size_t)(32 + tb) * 8 + ks) * 64 + lane) * 8);
#pragma unroll
                    for (int mt = 0; mt < 2; mt++) {
                        accr[mt][nt] = __builtin_amdgcn_mfma_f32_16x16x32_bf16(a[mt], br, accr[mt][nt], 0, 0, 0);
                        accz[mt][nt] = __builtin_amdgcn_mfma_f32_16x16x32_bf16(a[mt], bz, accz[mt][nt], 0, 0, 0);
                        accn[mt][nt] = __builtin_amdgcn_mfma_f32_16x16x32_bf16(a[mt], bn, accn[mt][nt], 0, 0, 0);
                    }
                }
            }
        }
        // ---------------- gates + state update (fp32) ----------------
#pragma unroll
        for (int mt = 0; mt < 2; mt++)
#pragma unroll
            for (int nt = 0; nt < 2; nt++) {
                const int u = w * 32 + nt * 16 + l15;
#pragma unroll
                for (int rr = 0; rr < 4; rr++) {
                    const int sl = mt * 16 + kg * 4 + rr;
                    const int sg = s0 + sl;
                    const int bv = p ? BYs[sl * PATCHL + p - 1] : 0;
                    const float* lg = latg + (size_t)sg * 768;
                    const float* pm = premix + (size_t)bv * 768;
                    const float xr = lg[u]       + pm[u];
                    const float xz = lg[u + 256] + pm[u + 256];
                    const float xn = lg[u + 512] + pm[u + 512];
                    const float r = sigf(xr + accr[mt][nt][rr] + bhr[nt]);
                    const float z = sigf(xz + accz[mt][nt][rr] + bhz[nt]);
                    const float n = tanhf_(xn + r * (accn[mt][nt][rr] + bhn[nt]));
                    const float hn_ = (1.f - z) * n + z * hreg[mt][nt][rr];
                    hreg[mt][nt][rr] = hn_;
                    const int bo = (2 * u) ^ ((sl & 7) << 4);   // XOR-swizzled bf16 store
                    Hnxt[sl * 256 + (bo >> 1)] = f2bf(hn_);
                }
            }
        __syncthreads();
        // ---------------- head: logits = h_new @ W_head^T ----------------
        f32x4 acch[2][2];
#pragma unroll
        for (int mt = 0; mt < 2; mt++)
#pragma unroll
            for (int nt = 0; nt < 2; nt++) acch[mt][nt] = 0.f;
#pragma unroll
        for (int ks = 0; ks < 8; ++ks) {
            bf16x8 a[2];
#pragma unroll
            for (int mt = 0; mt < 2; mt++) {
                const int s = mt * 16 + l15;
                const int off = (ks * 64 + kg * 16) ^ ((s & 7) << 4);
                a[mt] = *(const bf16x8*)(Hnxt + s * 256 + (off >> 1));
            }
#pragma unroll
            for (int nt = 0; nt < 2; nt++) {
                const int tb = w * 2 + nt;
                const bf16x8 bh = *(const bf16x8*)(wp_hd + (((size_t)tb * 8 + ks) * 64 + lane) * 8);
#pragma unroll
                for (int mt = 0; mt < 2; mt++)
                    acch[mt][nt] = __builtin_amdgcn_mfma_f32_16x16x32_bf16(a[mt], bh, acch[mt][nt], 0, 0, 0);
            }
        }
#pragma unroll
        for (int mt = 0; mt < 2; mt++)
#pragma unroll
            for (int nt = 0; nt < 2; nt++) {
                const int u = w * 32 + nt * 16 + l15;
#pragma unroll
                for (int rr = 0; rr < 4; rr++) {
                    const int sl = mt * 16 + kg * 4 + rr;
                    out[((size_t)(s0 + sl) * PATCHL + p) * VOCABN + u] = acch[mt][nt][rr] + bhd[nt];
                }
            }
        // swap buffers; single barrier per step is sufficient (see header)
        unsigned short* t_ = Hcur; Hcur = Hnxt; Hnxt = t_;
    }
}

// ---------------------------------------------------------------------------
extern "C" void kernel_launch(void* const* d_in, const int* in_sizes, int n_in,
                              void* d_out, int out_size, void* d_ws, size_t ws_size,
                              hipStream_t stream)
{
    const float* latents = (const float*)d_in[0];   // [8192][1024]
    const int*   tb      = (const int*)d_in[1];     // [8192*16]
    const float* W_proj  = (const float*)d_in[2];   // [256][1024]
    const float* b_proj  = (const float*)d_in[3];   // [256]
    const float* emb     = (const float*)d_in[4];   // [256][256]
    const float* W_ih    = (const float*)d_in[5];   // [768][512]
    const float* W_hh    = (const float*)d_in[6];   // [768][256]
    const float* b_ih    = (const float*)d_in[7];   // [768]
    const float* b_hh    = (const float*)d_in[8];   // [768]
    const float* W_head  = (const float*)d_in[9];   // [256][256]
    const float* b_head  = (const float*)d_in[10];  // [256]
    float* out = (float*)d_out;

    float* ws     = (float*)d_ws;
    float* latg   = ws;                                   // 8192*768 f32
    float* ctx    = ws + (size_t)NSEQ * 768;              // 8192*256 f32
    float* premix = ctx + (size_t)NSEQ * HIDN;            // 256*768 f32
    unsigned short* wpack = (unsigned short*)(premix + 256 * 768);  // 64*8*64*8 bf16

    // ctx = latents @ W_proj^T + b_proj
    hipLaunchKernelGGL((gemm_nt<64, 64, 16>), dim3(NSEQ / 64, 4), dim3(256), 0, stream,
                       latents, W_proj, b_proj, ctx, 1024, 1024, 1024, 256);
    // latg = ctx @ W_ih[:,256:512]^T + b_ih
    hipLaunchKernelGGL((gemm_nt<64, 64, 16>), dim3(NSEQ / 64, 12), dim3(256), 0, stream,
                       ctx, W_ih + 256, b_ih, latg, 256, 256, 512, 768);
    // premix = emb_table @ W_ih[:,0:256]^T
    hipLaunchKernelGGL((gemm_nt<64, 64, 16>), dim3(4, 12), dim3(256), 0, stream,
                       emb, W_ih, nullptr, premix, 256, 256, 512, 768);
    // bf16 fragment-ordered weight pack
    hipLaunchKernelGGL(pack_weights, dim3(128), dim3(256), 0, stream, W_hh, W_head, wpack);
    // fused MFMA GRU scan + head
    hipLaunchKernelGGL(gru_head_mfma, dim3(NSEQ / 32), dim3(512), 0, stream,
                       tb, latg, premix, wpack, b_hh, b_head, out);
}

// Round 3
// 528.844 us; speedup vs baseline: 3.6420x; 1.2468x over previous
//
#include <hip/hip_runtime.h>
#include <math.h>

// Problem constants
#define NSEQ 8192          // B*N
#define PATCHL 16
#define HIDN 256
#define VOCABN 256

typedef __attribute__((ext_vector_type(4))) float f32x4;
typedef __attribute__((ext_vector_type(8))) short bf16x8;   // 8 bf16 = 4 VGPRs

__device__ __forceinline__ unsigned short f2bf(float f) {
    unsigned int x = __float_as_uint(f);
    unsigned int r = (x + 0x7fffu + ((x >> 16) & 1u)) >> 16;
    return (unsigned short)r;
}
__device__ __forceinline__ float sigf(float x)   { return 1.f / (1.f + __expf(-x)); }
__device__ __forceinline__ float tanhf_(float x) { return 2.f / (1.f + __expf(-2.f * x)) - 1.f; }

// ---------------------------------------------------------------------------
// fp32 tiled GEMM (round-1, verified). Only used for the tiny premix GEMM.
// ---------------------------------------------------------------------------
template<int BM, int BN, int BK>
__global__ __launch_bounds__(256)
void gemm_nt(const float* __restrict__ A, const float* __restrict__ B,
             const float* __restrict__ bias, float* __restrict__ C,
             int K, int lda, int ldb, int ldc)
{
    __shared__ float As[BM][BK + 1];
    __shared__ float Bs[BN][BK + 1];
    const int t  = threadIdx.x;
    const int bm = blockIdx.x * BM;
    const int bn = blockIdx.y * BN;
    const int tx = t & 15, ty = t >> 4;

    float acc[4][4];
#pragma unroll
    for (int i = 0; i < 4; i++)
#pragma unroll
        for (int j = 0; j < 4; j++) acc[i][j] = 0.f;

    const int row = t >> 2;
    const int seg = (t & 3) * 4;

    for (int k0 = 0; k0 < K; k0 += BK) {
        float4 a4 = *(const float4*)(A + (size_t)(bm + row) * lda + k0 + seg);
        float4 b4 = *(const float4*)(B + (size_t)(bn + row) * ldb + k0 + seg);
        As[row][seg + 0] = a4.x; As[row][seg + 1] = a4.y;
        As[row][seg + 2] = a4.z; As[row][seg + 3] = a4.w;
        Bs[row][seg + 0] = b4.x; Bs[row][seg + 1] = b4.y;
        Bs[row][seg + 2] = b4.z; Bs[row][seg + 3] = b4.w;
        __syncthreads();
#pragma unroll
        for (int kk = 0; kk < BK; kk++) {
            float a[4], b[4];
#pragma unroll
            for (int i = 0; i < 4; i++) a[i] = As[ty * 4 + i][kk];
#pragma unroll
            for (int j = 0; j < 4; j++) b[j] = Bs[tx * 4 + j][kk];
#pragma unroll
            for (int i = 0; i < 4; i++)
#pragma unroll
                for (int j = 0; j < 4; j++) acc[i][j] += a[i] * b[j];
        }
        __syncthreads();
    }

#pragma unroll
    for (int i = 0; i < 4; i++) {
        const int m = bm + ty * 4 + i;
        const int n = bn + tx * 4;
        float4 v;
        v.x = acc[i][0]; v.y = acc[i][1]; v.z = acc[i][2]; v.w = acc[i][3];
        if (bias) { v.x += bias[n]; v.y += bias[n + 1]; v.z += bias[n + 2]; v.w += bias[n + 3]; }
        *(float4*)(C + (size_t)m * ldc + n) = v;
    }
}

// ---------------------------------------------------------------------------
// Fragment-order bf16 pack of a weight matrix slice (MFMA B operand):
//   dst[((T*nks + ks)*64 + lane)*8 + j] =
//        bf16( src[(T*16 + (lane&15))*ld + col0 + ks*32 + ((lane>>4)&3)*8 + j] )
// ---------------------------------------------------------------------------
__global__ __launch_bounds__(256)
void pack_frag(const float* __restrict__ src, int ld, int col0, int nks,
               unsigned short* __restrict__ dst)
{
    const int g = blockIdx.x * 256 + threadIdx.x;
    const int lane = g & 63;
    const int ks = (g / 64) % nks;
    const int T  = g / (64 * nks);
    const float* s = src + (size_t)(T * 16 + (lane & 15)) * ld + col0 + ks * 32 + ((lane >> 4) & 3) * 8;
    unsigned int q[4];
#pragma unroll
    for (int j = 0; j < 4; j++) {
        unsigned int lo = f2bf(s[2 * j]);
        unsigned int hi = f2bf(s[2 * j + 1]);
        q[j] = lo | (hi << 16);
    }
    uint4 v; v.x = q[0]; v.y = q[1]; v.z = q[2]; v.w = q[3];
    *(uint4*)(dst + (size_t)g * 8) = v;
}

// premixP[bv*1024 + u*4 + g] = premix_raw[bv*768 + g*256 + u]   (g=0,1,2)
__global__ __launch_bounds__(768)
void repack_premix(const float* __restrict__ raw, float* __restrict__ pp)
{
    const int bv = blockIdx.x;
    const int u = threadIdx.x & 255;
    const int g = threadIdx.x >> 8;
    pp[(size_t)bv * 1024 + u * 4 + g] = raw[(size_t)bv * 768 + g * 256 + u];
}

// ---------------------------------------------------------------------------
// bf16 MFMA GEMM: C[m][n] = sum_k A[m][k] * W[n][k] (+bias[n])
// BM=128 BN=64 BK=64, 512 threads (8 waves), wave w owns rows w*16..w*16+15.
// ---------------------------------------------------------------------------
template<bool ASRC_BF16, bool OUT_BF16>
__global__ __launch_bounds__(512)
void gemm_mfma(const void* __restrict__ Asrc, int lda,
               const unsigned short* __restrict__ bpack, int nks_total,
               const float* __restrict__ bias, void* __restrict__ Cdst, int ldc,
               int K)
{
    const int tid = threadIdx.x;
    const int w = tid >> 6, lane = tid & 63;
    const int l15 = lane & 15, kg = (lane >> 4) & 3;
    const int bm = blockIdx.x * 128, bn = blockIdx.y * 64;

    __shared__ unsigned short As[2][128 * 64];

    const int srow = tid >> 2;           // 0..127
    const int scol = (tid & 3) * 16;     // 0,16,32,48
    const int nkt = K / 64;

    f32x4 acc[4];
#pragma unroll
    for (int nt = 0; nt < 4; nt++) acc[nt] = 0.f;

    const int wb0 = srow * 128 + ((scol * 2) ^ ((srow & 7) << 4));
    const int wb1 = srow * 128 + ((scol * 2 + 16) ^ ((srow & 7) << 4));

#define STAGE(kt, buf) do {                                                         \
        const int gk = (kt) * 64 + scol;                                            \
        unsigned short tmp[16];                                                     \
        if (ASRC_BF16) {                                                            \
            const unsigned short* A = (const unsigned short*)Asrc;                  \
            *(uint4*)(tmp)     = *(const uint4*)(A + (size_t)(bm + srow) * lda + gk);      \
            *(uint4*)(tmp + 8) = *(const uint4*)(A + (size_t)(bm + srow) * lda + gk + 8);  \
        } else {                                                                    \
            const float* A = (const float*)Asrc;                                    \
            const float4 a0 = *(const float4*)(A + (size_t)(bm + srow) * lda + gk);       \
            const float4 a1 = *(const float4*)(A + (size_t)(bm + srow) * lda + gk + 4);   \
            const float4 a2 = *(const float4*)(A + (size_t)(bm + srow) * lda + gk + 8);   \
            const float4 a3 = *(const float4*)(A + (size_t)(bm + srow) * lda + gk + 12);  \
            tmp[0] = f2bf(a0.x);  tmp[1] = f2bf(a0.y);  tmp[2] = f2bf(a0.z);  tmp[3] = f2bf(a0.w);   \
            tmp[4] = f2bf(a1.x);  tmp[5] = f2bf(a1.y);  tmp[6] = f2bf(a1.z);  tmp[7] = f2bf(a1.w);   \
            tmp[8] = f2bf(a2.x);  tmp[9] = f2bf(a2.y);  tmp[10] = f2bf(a2.z); tmp[11] = f2bf(a2.w);  \
            tmp[12] = f2bf(a3.x); tmp[13] = f2bf(a3.y); tmp[14] = f2bf(a3.z); tmp[15] = f2bf(a3.w);  \
        }                                                                           \
        *(uint4*)((char*)As[buf] + wb0) = *(uint4*)tmp;                             \
        *(uint4*)((char*)As[buf] + wb1) = *(uint4*)(tmp + 8);                       \
    } while (0)

    STAGE(0, 0);
    __syncthreads();

    for (int kt = 0; kt < nkt; ++kt) {
        if (kt + 1 < nkt) STAGE(kt + 1, (kt + 1) & 1);
        const unsigned short* buf = As[kt & 1];
        const int row = w * 16 + l15;
#pragma unroll
        for (int ks = 0; ks < 2; ++ks) {
            const int bo = row * 128 + (((ks * 64) + kg * 16) ^ ((row & 7) << 4));
            const bf16x8 a = *(const bf16x8*)((const char*)buf + bo);
#pragma unroll
            for (int nt = 0; nt < 4; ++nt) {
                const int T = blockIdx.y * 4 + nt;
                const bf16x8 b = *(const bf16x8*)(bpack + (((size_t)T * nks_total + (kt * 2 + ks)) * 64 + lane) * 8);
                acc[nt] = __builtin_amdgcn_mfma_f32_16x16x32_bf16(a, b, acc[nt], 0, 0, 0);
            }
        }
        __syncthreads();
    }
#undef STAGE

#pragma unroll
    for (int nt = 0; nt < 4; ++nt) {
        const int n = bn + nt * 16 + l15;
        const float bv = bias ? bias[n] : 0.f;
#pragma unroll
        for (int rr = 0; rr < 4; ++rr) {
            const int m = bm + w * 16 + kg * 4 + rr;
            const float v = acc[nt][rr] + bv;
            if (OUT_BF16) ((unsigned short*)Cdst)[(size_t)m * ldc + n] = f2bf(v);
            else          ((float*)Cdst)[(size_t)m * ldc + n] = v;
        }
    }
}

// ---------------------------------------------------------------------------
// MFMA GRU scan + head (round-2 verified structure) with latg hoisted into
// registers and premix gathered as one float4 per (seq,step).
// ---------------------------------------------------------------------------
__global__ __launch_bounds__(512)
void gru_head_mfma(const int* __restrict__ bytes,
                   const float* __restrict__ latg,     // [NSEQ][768], incl b_ih
                   const float* __restrict__ premixP,  // [256][1024] (r,z,n,pad)
                   const unsigned short* __restrict__ wpack,
                   const float* __restrict__ b_hh,     // [768]
                   const float* __restrict__ b_head,   // [256]
                   float* __restrict__ out)            // [NSEQ][16][256]
{
    const int tid  = threadIdx.x;
    const int w    = tid >> 6;
    const int lane = tid & 63;
    const int l15  = lane & 15;
    const int kg   = (lane >> 4) & 3;
    const int s0   = blockIdx.x * 32;

    __shared__ unsigned short H0[32 * 256];
    __shared__ unsigned short H1[32 * 256];
    __shared__ int BYs[512];

    BYs[tid] = bytes[s0 * PATCHL + tid];
    __syncthreads();

    const unsigned short* wp_hd = wpack + 48 * 8 * 64 * 8;

    float bhr[2], bhz[2], bhn[2], bhd[2];
#pragma unroll
    for (int nt = 0; nt < 2; nt++) {
        const int u = w * 32 + nt * 16 + l15;
        bhr[nt] = b_hh[u]; bhz[nt] = b_hh[256 + u]; bhn[nt] = b_hh[512 + u];
        bhd[nt] = b_head[u];
    }

    // step-invariant input-gate pre-activations -> registers
    // (r,z include their recurrent bias; n's bias stays separate: n uses r*(accn+bhn))
    float lgr[2][2][4], lgz[2][2][4], lgn[2][2][4];
#pragma unroll
    for (int mt = 0; mt < 2; mt++)
#pragma unroll
        for (int nt = 0; nt < 2; nt++) {
            const int u = w * 32 + nt * 16 + l15;
#pragma unroll
            for (int rr = 0; rr < 4; rr++) {
                const int sg = s0 + mt * 16 + kg * 4 + rr;
                const float* lg = latg + (size_t)sg * 768;
                lgr[mt][nt][rr] = lg[u]       + bhr[nt];
                lgz[mt][nt][rr] = lg[u + 256] + bhz[nt];
                lgn[mt][nt][rr] = lg[u + 512];
            }
        }

    float hreg[2][2][4];
#pragma unroll
    for (int mt = 0; mt < 2; mt++)
#pragma unroll
        for (int nt = 0; nt < 2; nt++)
#pragma unroll
            for (int rr = 0; rr < 4; rr++) hreg[mt][nt][rr] = 0.f;

    unsigned short* Hcur = H0;
    unsigned short* Hnxt = H1;

    for (int p = 0; p < PATCHL; ++p) {
        // ---------------- recurrence: hg = h_prev @ W_hh^T ----------------
        f32x4 accr[2][2], accz[2][2], accn[2][2];
#pragma unroll
        for (int mt = 0; mt < 2; mt++)
#pragma unroll
            for (int nt = 0; nt < 2; nt++) {
                accr[mt][nt] = 0.f; accz[mt][nt] = 0.f; accn[mt][nt] = 0.f;
            }
        if (p != 0) {
#pragma unroll
            for (int ks = 0; ks < 8; ++ks) {
                bf16x8 a[2];
#pragma unroll
                for (int mt = 0; mt < 2; mt++) {
                    const int s = mt * 16 + l15;
                    const int off = (ks * 64 + kg * 16) ^ ((s & 7) << 4);
                    a[mt] = *(const bf16x8*)(Hcur + s * 256 + (off >> 1));
                }
#pragma unroll
                for (int nt = 0; nt < 2; nt++) {
                    const int tb = w * 2 + nt;
                    const bf16x8 br = *(const bf16x8*)(wpack + (((size_t)(tb)      * 8 + ks) * 64 + lane) * 8);
                    const bf16x8 bz = *(const bf16x8*)(wpack + (((size_t)(16 + tb) * 8 + ks) * 64 + lane) * 8);
                    const bf16x8 bn = *(const bf16x8*)(wpack + (((size_t)(32 + tb) * 8 + ks) * 64 + lane) * 8);
#pragma unroll
                    for (int mt = 0; mt < 2; mt++) {
                        accr[mt][nt] = __builtin_amdgcn_mfma_f32_16x16x32_bf16(a[mt], br, accr[mt][nt], 0, 0, 0);
                        accz[mt][nt] = __builtin_amdgcn_mfma_f32_16x16x32_bf16(a[mt], bz, accz[mt][nt], 0, 0, 0);
                        accn[mt][nt] = __builtin_amdgcn_mfma_f32_16x16x32_bf16(a[mt], bn, accn[mt][nt], 0, 0, 0);
                    }
                }
            }
        }
        // ---------------- gates + state update (fp32) ----------------
#pragma unroll
        for (int mt = 0; mt < 2; mt++)
#pragma unroll
            for (int nt = 0; nt < 2; nt++) {
                const int u = w * 32 + nt * 16 + l15;
#pragma unroll
                for (int rr = 0; rr < 4; rr++) {
                    const int sl = mt * 16 + kg * 4 + rr;
                    const int bv = p ? BYs[sl * PATCHL + p - 1] : 0;
                    const f32x4 pm4 = *(const f32x4*)(premixP + (size_t)bv * 1024 + u * 4);
                    const float r = sigf(lgr[mt][nt][rr] + pm4[0] + accr[mt][nt][rr]);
                    const float z = sigf(lgz[mt][nt][rr] + pm4[1] + accz[mt][nt][rr]);
                    const float n = tanhf_(lgn[mt][nt][rr] + pm4[2] + r * (accn[mt][nt][rr] + bhn[nt]));
                    const float hn_ = (1.f - z) * n + z * hreg[mt][nt][rr];
                    hreg[mt][nt][rr] = hn_;
                    const int bo = (2 * u) ^ ((sl & 7) << 4);
                    Hnxt[sl * 256 + (bo >> 1)] = f2bf(hn_);
                }
            }
        __syncthreads();
        // ---------------- head: logits = h_new @ W_head^T ----------------
        f32x4 acch[2][2];
#pragma unroll
        for (int mt = 0; mt < 2; mt++)
#pragma unroll
            for (int nt = 0; nt < 2; nt++) acch[mt][nt] = 0.f;
#pragma unroll
        for (int ks = 0; ks < 8; ++ks) {
            bf16x8 a[2];
#pragma unroll
            for (int mt = 0; mt < 2; mt++) {
                const int s = mt * 16 + l15;
                const int off = (ks * 64 + kg * 16) ^ ((s & 7) << 4);
                a[mt] = *(const bf16x8*)(Hnxt + s * 256 + (off >> 1));
            }
#pragma unroll
            for (int nt = 0; nt < 2; nt++) {
                const int tb = w * 2 + nt;
                const bf16x8 bh = *(const bf16x8*)(wp_hd + (((size_t)tb * 8 + ks) * 64 + lane) * 8);
#pragma unroll
                for (int mt = 0; mt < 2; mt++)
                    acch[mt][nt] = __builtin_amdgcn_mfma_f32_16x16x32_bf16(a[mt], bh, acch[mt][nt], 0, 0, 0);
            }
        }
#pragma unroll
        for (int mt = 0; mt < 2; mt++)
#pragma unroll
            for (int nt = 0; nt < 2; nt++) {
                const int u = w * 32 + nt * 16 + l15;
#pragma unroll
                for (int rr = 0; rr < 4; rr++) {
                    const int sl = mt * 16 + kg * 4 + rr;
                    out[((size_t)(s0 + sl) * PATCHL + p) * VOCABN + u] = acch[mt][nt][rr] + bhd[nt];
                }
            }
        unsigned short* t_ = Hcur; Hcur = Hnxt; Hnxt = t_;
    }
}

// ---------------------------------------------------------------------------
extern "C" void kernel_launch(void* const* d_in, const int* in_sizes, int n_in,
                              void* d_out, int out_size, void* d_ws, size_t ws_size,
                              hipStream_t stream)
{
    const float* latents = (const float*)d_in[0];   // [8192][1024]
    const int*   tb      = (const int*)d_in[1];     // [8192*16]
    const float* W_proj  = (const float*)d_in[2];   // [256][1024]
    const float* b_proj  = (const float*)d_in[3];   // [256]
    const float* emb     = (const float*)d_in[4];   // [256][256]
    const float* W_ih    = (const float*)d_in[5];   // [768][512]
    const float* W_hh    = (const float*)d_in[6];   // [768][256]
    const float* b_ih    = (const float*)d_in[7];   // [768]
    const float* b_hh    = (const float*)d_in[8];   // [768]
    const float* W_head  = (const float*)d_in[9];   // [256][256]
    const float* b_head  = (const float*)d_in[10];  // [256]
    float* out = (float*)d_out;

    float* ws          = (float*)d_ws;
    float* latg        = ws;                                   // 8192*768 f32
    float* premixP     = latg + (size_t)NSEQ * 768;            // 256*1024 f32
    float* premix_raw  = premixP + 256 * 1024;                 // 256*768 f32
    unsigned short* ctxb   = (unsigned short*)(premix_raw + 256 * 768);  // 8192*256 bf16
    unsigned short* wpack  = ctxb + (size_t)NSEQ * HIDN;       // 64*8*64*8 bf16
    unsigned short* bpack1 = wpack + 64 * 8 * 64 * 8;          // 16*32*64*8 bf16
    unsigned short* bpack2 = bpack1 + 16 * 32 * 64 * 8;        // 48*8*64*8 bf16

    // weight packs (fragment-ordered bf16)
    hipLaunchKernelGGL(pack_frag, dim3(16 * 32 * 64 / 256), dim3(256), 0, stream,
                       W_proj, 1024, 0, 32, bpack1);
    hipLaunchKernelGGL(pack_frag, dim3(48 * 8 * 64 / 256), dim3(256), 0, stream,
                       W_ih, 512, 256, 8, bpack2);
    hipLaunchKernelGGL(pack_frag, dim3(48 * 8 * 64 / 256), dim3(256), 0, stream,
                       W_hh, 256, 0, 8, wpack);
    hipLaunchKernelGGL(pack_frag, dim3(16 * 8 * 64 / 256), dim3(256), 0, stream,
                       W_head, 256, 0, 8, wpack + 48 * 8 * 64 * 8);

    // premix = emb @ W_ih[:,0:256]^T (fp32), repacked to float4 gather form
    hipLaunchKernelGGL((gemm_nt<64, 64, 16>), dim3(4, 12), dim3(256), 0, stream,
                       emb, W_ih, nullptr, premix_raw, 256, 256, 512, 768);
    hipLaunchKernelGGL(repack_premix, dim3(256), dim3(768), 0, stream, premix_raw, premixP);

    // ctx(bf16) = latents @ W_proj^T + b_proj
    hipLaunchKernelGGL((gemm_mfma<false, true>), dim3(NSEQ / 128, 4), dim3(512), 0, stream,
                       latents, 1024, bpack1, 32, b_proj, ctxb, 256, 1024);
    // latg(f32) = ctx @ W_ih[:,256:512]^T + b_ih
    hipLaunchKernelGGL((gemm_mfma<true, false>), dim3(NSEQ / 128, 12), dim3(512), 0, stream,
                       ctxb, 256, bpack2, 8, b_ih, latg, 768, 256);

    // fused MFMA GRU scan + head
    hipLaunchKernelGGL(gru_head_mfma, dim3(NSEQ / 32), dim3(512), 0, stream,
                       tb, latg, premixP, wpack, b_hh, b_head, out);
}

// Round 4
// 525.525 us; speedup vs baseline: 3.6650x; 1.0063x over previous
//
#include <hip/hip_runtime.h>
#include <math.h>

// Problem constants
#define NSEQ 8192          // B*N
#define PATCHL 16
#define HIDN 256
#define VOCABN 256

typedef __attribute__((ext_vector_type(4))) float f32x4;
typedef __attribute__((ext_vector_type(8))) short bf16x8;   // 8 bf16 = 4 VGPRs

__device__ __forceinline__ unsigned short f2bf(float f) {
    unsigned int x = __float_as_uint(f);
    unsigned int r = (x + 0x7fffu + ((x >> 16) & 1u)) >> 16;
    return (unsigned short)r;
}
__device__ __forceinline__ float bf2f(unsigned short b) {
    return __uint_as_float(((unsigned int)b) << 16);
}
__device__ __forceinline__ float sigf(float x)   { return 1.f / (1.f + __expf(-x)); }
__device__ __forceinline__ float tanhf_(float x) { return 2.f / (1.f + __expf(-2.f * x)) - 1.f; }

// ---------------------------------------------------------------------------
// Fragment-order bf16 pack of a weight matrix slice (MFMA B operand):
//   dst[((T*nks + ks)*64 + lane)*8 + j] =
//        bf16( src[(T*16 + (lane&15))*ld + col0 + ks*32 + ((lane>>4)&3)*8 + j] )
// ---------------------------------------------------------------------------
__global__ __launch_bounds__(256)
void pack_frag(const float* __restrict__ src, int ld, int col0, int nks,
               unsigned short* __restrict__ dst)
{
    const int g = blockIdx.x * 256 + threadIdx.x;
    const int lane = g & 63;
    const int ks = (g / 64) % nks;
    const int T  = g / (64 * nks);
    const float* s = src + (size_t)(T * 16 + (lane & 15)) * ld + col0 + ks * 32 + ((lane >> 4) & 3) * 8;
    unsigned int q[4];
#pragma unroll
    for (int j = 0; j < 4; j++) {
        unsigned int lo = f2bf(s[2 * j]);
        unsigned int hi = f2bf(s[2 * j + 1]);
        q[j] = lo | (hi << 16);
    }
    uint4 v; v.x = q[0]; v.y = q[1]; v.z = q[2]; v.w = q[3];
    *(uint4*)(dst + (size_t)g * 8) = v;
}

// ---------------------------------------------------------------------------
// bf16 MFMA GEMM: C[m][n] = sum_k A[m][k] * W[n][k] (+bias[n])
// BM=128 BN=64 BK=64, 512 threads (8 waves). Verified round 3.
// ---------------------------------------------------------------------------
template<bool ASRC_BF16, bool OUT_BF16>
__global__ __launch_bounds__(512)
void gemm_mfma(const void* __restrict__ Asrc, int lda,
               const unsigned short* __restrict__ bpack, int nks_total,
               const float* __restrict__ bias, void* __restrict__ Cdst, int ldc,
               int K)
{
    const int tid = threadIdx.x;
    const int w = tid >> 6, lane = tid & 63;
    const int l15 = lane & 15, kg = (lane >> 4) & 3;
    const int bm = blockIdx.x * 128, bn = blockIdx.y * 64;

    __shared__ unsigned short As[2][128 * 64];

    const int srow = tid >> 2;           // 0..127
    const int scol = (tid & 3) * 16;     // 0,16,32,48
    const int nkt = K / 64;

    f32x4 acc[4];
#pragma unroll
    for (int nt = 0; nt < 4; nt++) acc[nt] = 0.f;

    const int wb0 = srow * 128 + ((scol * 2) ^ ((srow & 7) << 4));
    const int wb1 = srow * 128 + ((scol * 2 + 16) ^ ((srow & 7) << 4));

#define STAGE(kt, buf) do {                                                         \
        const int gk = (kt) * 64 + scol;                                            \
        unsigned short tmp[16];                                                     \
        if (ASRC_BF16) {                                                            \
            const unsigned short* A = (const unsigned short*)Asrc;                  \
            *(uint4*)(tmp)     = *(const uint4*)(A + (size_t)(bm + srow) * lda + gk);      \
            *(uint4*)(tmp + 8) = *(const uint4*)(A + (size_t)(bm + srow) * lda + gk + 8);  \
        } else {                                                                    \
            const float* A = (const float*)Asrc;                                    \
            const float4 a0 = *(const float4*)(A + (size_t)(bm + srow) * lda + gk);       \
            const float4 a1 = *(const float4*)(A + (size_t)(bm + srow) * lda + gk + 4);   \
            const float4 a2 = *(const float4*)(A + (size_t)(bm + srow) * lda + gk + 8);   \
            const float4 a3 = *(const float4*)(A + (size_t)(bm + srow) * lda + gk + 12);  \
            tmp[0] = f2bf(a0.x);  tmp[1] = f2bf(a0.y);  tmp[2] = f2bf(a0.z);  tmp[3] = f2bf(a0.w);   \
            tmp[4] = f2bf(a1.x);  tmp[5] = f2bf(a1.y);  tmp[6] = f2bf(a1.z);  tmp[7] = f2bf(a1.w);   \
            tmp[8] = f2bf(a2.x);  tmp[9] = f2bf(a2.y);  tmp[10] = f2bf(a2.z); tmp[11] = f2bf(a2.w);  \
            tmp[12] = f2bf(a3.x); tmp[13] = f2bf(a3.y); tmp[14] = f2bf(a3.z); tmp[15] = f2bf(a3.w);  \
        }                                                                           \
        *(uint4*)((char*)As[buf] + wb0) = *(uint4*)tmp;                             \
        *(uint4*)((char*)As[buf] + wb1) = *(uint4*)(tmp + 8);                       \
    } while (0)

    STAGE(0, 0);
    __syncthreads();

    for (int kt = 0; kt < nkt; ++kt) {
        if (kt + 1 < nkt) STAGE(kt + 1, (kt + 1) & 1);
        const unsigned short* buf = As[kt & 1];
        const int row = w * 16 + l15;
#pragma unroll
        for (int ks = 0; ks < 2; ++ks) {
            const int bo = row * 128 + (((ks * 64) + kg * 16) ^ ((row & 7) << 4));
            const bf16x8 a = *(const bf16x8*)((const char*)buf + bo);
#pragma unroll
            for (int nt = 0; nt < 4; ++nt) {
                const int T = blockIdx.y * 4 + nt;
                const bf16x8 b = *(const bf16x8*)(bpack + (((size_t)T * nks_total + (kt * 2 + ks)) * 64 + lane) * 8);
                acc[nt] = __builtin_amdgcn_mfma_f32_16x16x32_bf16(a, b, acc[nt], 0, 0, 0);
            }
        }
        __syncthreads();
    }
#undef STAGE

#pragma unroll
    for (int nt = 0; nt < 4; ++nt) {
        const int n = bn + nt * 16 + l15;
        const float bv = bias ? bias[n] : 0.f;
#pragma unroll
        for (int rr = 0; rr < 4; ++rr) {
            const int m = bm + w * 16 + kg * 4 + rr;
            const float v = acc[nt][rr] + bv;
            if (OUT_BF16) ((unsigned short*)Cdst)[(size_t)m * ldc + n] = f2bf(v);
            else          ((float*)Cdst)[(size_t)m * ldc + n] = v;
        }
    }
}

// ---------------------------------------------------------------------------
// xg producer: xg[(seq-seq0)*16 + p][g*256 + u] = bf16(latg[seq][g*256+u]
//                                                + premixB[byte(seq,p)][g*256+u])
// grid (SPC/32, 3); 512 threads. premix g-slice staged in LDS (128 KB) so the
// per-(seq,p) byte gather never leaves the CU. All global traffic streaming.
// ---------------------------------------------------------------------------
__global__ __launch_bounds__(512)
void xg_producer(const int* __restrict__ bytes,          // [NSEQ*16]
                 const float* __restrict__ latg,         // [NSEQ][768]
                 const unsigned short* __restrict__ premixB, // [256][768] bf16
                 unsigned short* __restrict__ xg,        // [SPC*16][768] bf16
                 int seq0)
{
    __shared__ unsigned short PM[256 * 256];   // 128 KB g-slice
    __shared__ int BY[32 * 16];

    const int tid = threadIdx.x;
    const int g = blockIdx.y;
    const int sblk = seq0 + blockIdx.x * 32;

    // stage premix g-slice: PM[bv][u] = premixB[bv*768 + g*256 + u]
#pragma unroll
    for (int j = 0; j < 16; ++j) {
        const int idx = j * 512 + tid;       // uint4 index (8 bf16)
        const int flat = idx * 8;
        const int bv = flat >> 8, u = flat & 255;
        *(uint4*)(PM + flat) = *(const uint4*)(premixB + (size_t)bv * 768 + g * 256 + u);
    }
    BY[tid & 511] = bytes[(size_t)sblk * PATCHL + (tid & 511)];
    __syncthreads();

    const int ug = (tid & 63) * 4;       // 4 consecutive gate units
    const int sg = tid >> 6;             // 0..7: seq sub-slot

    for (int si = 0; si < 4; ++si) {
        const int sl = si * 8 + sg;      // 0..31
        const int seq = sblk + sl;
        const float4 lat = *(const float4*)(latg + (size_t)seq * 768 + g * 256 + ug);
        unsigned short* dst = xg + ((size_t)(seq - seq0) * PATCHL) * 768 + g * 256 + ug;
#pragma unroll
        for (int p = 0; p < PATCHL; ++p) {
            const int bv = p ? BY[sl * PATCHL + p - 1] : 0;
            const ushort4 pm = *(const ushort4*)(PM + bv * 256 + ug);
            ushort4 o;
            o.x = f2bf(lat.x + bf2f(pm.x));
            o.y = f2bf(lat.y + bf2f(pm.y));
            o.z = f2bf(lat.z + bf2f(pm.z));
            o.w = f2bf(lat.w + bf2f(pm.w));
            *(ushort4*)(dst + (size_t)p * 768) = o;
        }
    }
}

// ---------------------------------------------------------------------------
// MFMA GRU scan + head. Gate inputs now stream from xg (bf16, coalesced,
// read exactly once) — no gathers, no byte table, no premix.
// ---------------------------------------------------------------------------
__global__ __launch_bounds__(512)
void gru_head_mfma(const unsigned short* __restrict__ xg,   // [SPC*16][768]
                   const unsigned short* __restrict__ wpack,
                   const float* __restrict__ b_hh,          // [768]
                   const float* __restrict__ b_head,        // [256]
                   float* __restrict__ out,                 // [NSEQ][16][256]
                   int seq0)
{
    const int tid  = threadIdx.x;
    const int w    = tid >> 6;
    const int lane = tid & 63;
    const int l15  = lane & 15;
    const int kg   = (lane >> 4) & 3;
    const int s0l  = blockIdx.x * 32;            // chunk-local
    const int s0g  = seq0 + s0l;                 // global

    __shared__ unsigned short H0[32 * 256];
    __shared__ unsigned short H1[32 * 256];

    const unsigned short* wp_hd = wpack + 48 * 8 * 64 * 8;

    float bhr[2], bhz[2], bhn[2], bhd[2];
#pragma unroll
    for (int nt = 0; nt < 2; nt++) {
        const int u = w * 32 + nt * 16 + l15;
        bhr[nt] = b_hh[u]; bhz[nt] = b_hh[256 + u]; bhn[nt] = b_hh[512 + u];
        bhd[nt] = b_head[u];
    }

    float hreg[2][2][4];
#pragma unroll
    for (int mt = 0; mt < 2; mt++)
#pragma unroll
        for (int nt = 0; nt < 2; nt++)
#pragma unroll
            for (int rr = 0; rr < 4; rr++) hreg[mt][nt][rr] = 0.f;

    unsigned short* Hcur = H0;
    unsigned short* Hnxt = H1;

    for (int p = 0; p < PATCHL; ++p) {
        // ---- gate-input loads first (independent of recurrence -> overlap) ----
        float xr[2][2][4], xz[2][2][4], xn[2][2][4];
#pragma unroll
        for (int mt = 0; mt < 2; mt++)
#pragma unroll
            for (int nt = 0; nt < 2; nt++) {
                const int u = w * 32 + nt * 16 + l15;
#pragma unroll
                for (int rr = 0; rr < 4; rr++) {
                    const int sl = mt * 16 + kg * 4 + rr;
                    const unsigned short* bp = xg + ((size_t)(s0l + sl) * PATCHL + p) * 768;
                    xr[mt][nt][rr] = bf2f(bp[u]);
                    xz[mt][nt][rr] = bf2f(bp[u + 256]);
                    xn[mt][nt][rr] = bf2f(bp[u + 512]);
                }
            }
        // ---------------- recurrence: hg = h_prev @ W_hh^T ----------------
        f32x4 accr[2][2], accz[2][2], accn[2][2];
#pragma unroll
        for (int mt = 0; mt < 2; mt++)
#pragma unroll
            for (int nt = 0; nt < 2; nt++) {
                accr[mt][nt] = 0.f; accz[mt][nt] = 0.f; accn[mt][nt] = 0.f;
            }
        if (p != 0) {
#pragma unroll
            for (int ks = 0; ks < 8; ++ks) {
                bf16x8 a[2];
#pragma unroll
                for (int mt = 0; mt < 2; mt++) {
                    const int s = mt * 16 + l15;
                    const int off = (ks * 64 + kg * 16) ^ ((s & 7) << 4);
                    a[mt] = *(const bf16x8*)(Hcur + s * 256 + (off >> 1));
                }
#pragma unroll
                for (int nt = 0; nt < 2; nt++) {
                    const int tb = w * 2 + nt;
                    const bf16x8 br = *(const bf16x8*)(wpack + (((size_t)(tb)      * 8 + ks) * 64 + lane) * 8);
                    const bf16x8 bz = *(const bf16x8*)(wpack + (((size_t)(16 + tb) * 8 + ks) * 64 + lane) * 8);
                    const bf16x8 bn = *(const bf16x8*)(wpack + (((size_t)(32 + tb) * 8 + ks) * 64 + lane) * 8);
#pragma unroll
                    for (int mt = 0; mt < 2; mt++) {
                        accr[mt][nt] = __builtin_amdgcn_mfma_f32_16x16x32_bf16(a[mt], br, accr[mt][nt], 0, 0, 0);
                        accz[mt][nt] = __builtin_amdgcn_mfma_f32_16x16x32_bf16(a[mt], bz, accz[mt][nt], 0, 0, 0);
                        accn[mt][nt] = __builtin_amdgcn_mfma_f32_16x16x32_bf16(a[mt], bn, accn[mt][nt], 0, 0, 0);
                    }
                }
            }
        }
        // ---------------- gates + state update (fp32) ----------------
#pragma unroll
        for (int mt = 0; mt < 2; mt++)
#pragma unroll
            for (int nt = 0; nt < 2; nt++) {
                const int u = w * 32 + nt * 16 + l15;
#pragma unroll
                for (int rr = 0; rr < 4; rr++) {
                    const int sl = mt * 16 + kg * 4 + rr;
                    const float r = sigf(xr[mt][nt][rr] + accr[mt][nt][rr] + bhr[nt]);
                    const float z = sigf(xz[mt][nt][rr] + accz[mt][nt][rr] + bhz[nt]);
                    const float n = tanhf_(xn[mt][nt][rr] + r * (accn[mt][nt][rr] + bhn[nt]));
                    const float hn_ = (1.f - z) * n + z * hreg[mt][nt][rr];
                    hreg[mt][nt][rr] = hn_;
                    const int bo = (2 * u) ^ ((sl & 7) << 4);
                    Hnxt[sl * 256 + (bo >> 1)] = f2bf(hn_);
                }
            }
        __syncthreads();
        // ---------------- head: logits = h_new @ W_head^T ----------------
        f32x4 acch[2][2];
#pragma unroll
        for (int mt = 0; mt < 2; mt++)
#pragma unroll
            for (int nt = 0; nt < 2; nt++) acch[mt][nt] = 0.f;
#pragma unroll
        for (int ks = 0; ks < 8; ++ks) {
            bf16x8 a[2];
#pragma unroll
            for (int mt = 0; mt < 2; mt++) {
                const int s = mt * 16 + l15;
                const int off = (ks * 64 + kg * 16) ^ ((s & 7) << 4);
                a[mt] = *(const bf16x8*)(Hnxt + s * 256 + (off >> 1));
            }
#pragma unroll
            for (int nt = 0; nt < 2; nt++) {
                const int tb = w * 2 + nt;
                const bf16x8 bh = *(const bf16x8*)(wp_hd + (((size_t)tb * 8 + ks) * 64 + lane) * 8);
#pragma unroll
                for (int mt = 0; mt < 2; mt++)
                    acch[mt][nt] = __builtin_amdgcn_mfma_f32_16x16x32_bf16(a[mt], bh, acch[mt][nt], 0, 0, 0);
            }
        }
#pragma unroll
        for (int mt = 0; mt < 2; mt++)
#pragma unroll
            for (int nt = 0; nt < 2; nt++) {
                const int u = w * 32 + nt * 16 + l15;
#pragma unroll
                for (int rr = 0; rr < 4; rr++) {
                    const int sl = mt * 16 + kg * 4 + rr;
                    out[((size_t)(s0g + sl) * PATCHL + p) * VOCABN + u] = acch[mt][nt][rr] + bhd[nt];
                }
            }
        unsigned short* t_ = Hcur; Hcur = Hnxt; Hnxt = t_;
    }
}

// ---------------------------------------------------------------------------
extern "C" void kernel_launch(void* const* d_in, const int* in_sizes, int n_in,
                              void* d_out, int out_size, void* d_ws, size_t ws_size,
                              hipStream_t stream)
{
    const float* latents = (const float*)d_in[0];   // [8192][1024]
    const int*   tb      = (const int*)d_in[1];     // [8192*16]
    const float* W_proj  = (const float*)d_in[2];   // [256][1024]
    const float* b_proj  = (const float*)d_in[3];   // [256]
    const float* emb     = (const float*)d_in[4];   // [256][256]
    const float* W_ih    = (const float*)d_in[5];   // [768][512]
    const float* W_hh    = (const float*)d_in[6];   // [768][256]
    const float* b_ih    = (const float*)d_in[7];   // [768]
    const float* b_hh    = (const float*)d_in[8];   // [768]
    const float* W_head  = (const float*)d_in[9];   // [256][256]
    const float* b_head  = (const float*)d_in[10];  // [256]
    float* out = (float*)d_out;

    // ---- workspace layout (bytes) ----
    char* w = (char*)d_ws;
    float* latg = (float*)w;                               w += (size_t)NSEQ * 768 * 4;     // 25.2 MB
    unsigned short* ctxb    = (unsigned short*)w;          w += (size_t)NSEQ * HIDN * 2;    // 4.2 MB
    unsigned short* premixB = (unsigned short*)w;          w += 256 * 768 * 2;              // 384 KB
    unsigned short* bpack1  = (unsigned short*)w;          w += 16 * 32 * 64 * 8 * 2;       // 512 KB
    unsigned short* bpack2  = (unsigned short*)w;          w += 48 * 8 * 64 * 8 * 2;        // 384 KB
    unsigned short* bpack3  = (unsigned short*)w;          w += 48 * 8 * 64 * 8 * 2;        // 384 KB
    unsigned short* wpack   = (unsigned short*)w;          w += 64 * 8 * 64 * 8 * 2;        // 512 KB
    unsigned short* xg      = (unsigned short*)w;
    const size_t fixed_bytes = (size_t)(w - (char*)d_ws);
    const size_t xg_full = (size_t)NSEQ * PATCHL * 768 * 2;            // 201.3 MB

    int nch = 1;
    while (nch < 16 && fixed_bytes + xg_full / nch > ws_size) nch <<= 1;
    const int SPC = NSEQ / nch;                    // seqs per chunk

    // ---- weight packs (fragment-ordered bf16) ----
    hipLaunchKernelGGL(pack_frag, dim3(128), dim3(256), 0, stream, W_proj, 1024, 0, 32, bpack1);
    hipLaunchKernelGGL(pack_frag, dim3(96),  dim3(256), 0, stream, W_ih,   512, 256, 8, bpack2);
    hipLaunchKernelGGL(pack_frag, dim3(96),  dim3(256), 0, stream, W_ih,   512, 0,   8, bpack3);
    hipLaunchKernelGGL(pack_frag, dim3(96),  dim3(256), 0, stream, W_hh,   256, 0,   8, wpack);
    hipLaunchKernelGGL(pack_frag, dim3(32),  dim3(256), 0, stream, W_head, 256, 0,   8, wpack + 48 * 8 * 64 * 8);

    // premixB(bf16) = emb @ W_ih[:,0:256]^T        [256][768]
    hipLaunchKernelGGL((gemm_mfma<false, true>), dim3(2, 12), dim3(512), 0, stream,
                       emb, 256, bpack3, 8, nullptr, premixB, 768, 256);
    // ctx(bf16) = latents @ W_proj^T + b_proj      [8192][256]
    hipLaunchKernelGGL((gemm_mfma<false, true>), dim3(NSEQ / 128, 4), dim3(512), 0, stream,
                       latents, 1024, bpack1, 32, b_proj, ctxb, 256, 1024);
    // latg(f32) = ctx @ W_ih[:,256:512]^T + b_ih   [8192][768]
    hipLaunchKernelGGL((gemm_mfma<true, false>), dim3(NSEQ / 128, 12), dim3(512), 0, stream,
                       ctxb, 256, bpack2, 8, b_ih, latg, 768, 256);

    // ---- per-chunk: xg producer then fused scan (stream-ordered) ----
    for (int c = 0; c < nch; ++c) {
        const int seq0 = c * SPC;
        hipLaunchKernelGGL(xg_producer, dim3(SPC / 32, 3), dim3(512), 0, stream,
                           tb, latg, premixB, xg, seq0);
        hipLaunchKernelGGL(gru_head_mfma, dim3(SPC / 32), dim3(512), 0, stream,
                           xg, wpack, b_hh, b_head, out, seq0);
    }
}

// Round 5
// 410.627 us; speedup vs baseline: 4.6906x; 1.2798x over previous
//
#include <hip/hip_runtime.h>
#include <math.h>

// Problem constants
#define NSEQ 8192          // B*N
#define PATCHL 16
#define HIDN 256
#define VOCABN 256

typedef __attribute__((ext_vector_type(4))) float f32x4;
typedef __attribute__((ext_vector_type(8))) short bf16x8;   // 8 bf16 = 4 VGPRs

__device__ __forceinline__ unsigned short f2bf(float f) {
    unsigned int x = __float_as_uint(f);
    unsigned int r = (x + 0x7fffu + ((x >> 16) & 1u)) >> 16;
    return (unsigned short)r;
}
__device__ __forceinline__ float bf2f(unsigned short b) {
    return __uint_as_float(((unsigned int)b) << 16);
}
__device__ __forceinline__ float sigf(float x)   { return 1.f / (1.f + __expf(-x)); }
__device__ __forceinline__ float tanhf_(float x) { return 2.f / (1.f + __expf(-2.f * x)) - 1.f; }

// ---------------------------------------------------------------------------
// Fragment-order bf16 pack of a weight matrix slice (MFMA B operand):
//   dst[((T*nks + ks)*64 + lane)*8 + j] =
//        bf16( src[(T*16 + (lane&15))*ld + col0 + ks*32 + ((lane>>4)&3)*8 + j] )
// ---------------------------------------------------------------------------
__global__ __launch_bounds__(256)
void pack_frag(const float* __restrict__ src, int ld, int col0, int nks,
               unsigned short* __restrict__ dst)
{
    const int g = blockIdx.x * 256 + threadIdx.x;
    const int lane = g & 63;
    const int ks = (g / 64) % nks;
    const int T  = g / (64 * nks);
    const float* s = src + (size_t)(T * 16 + (lane & 15)) * ld + col0 + ks * 32 + ((lane >> 4) & 3) * 8;
    unsigned int q[4];
#pragma unroll
    for (int j = 0; j < 4; j++) {
        unsigned int lo = f2bf(s[2 * j]);
        unsigned int hi = f2bf(s[2 * j + 1]);
        q[j] = lo | (hi << 16);
    }
    uint4 v; v.x = q[0]; v.y = q[1]; v.z = q[2]; v.w = q[3];
    *(uint4*)(dst + (size_t)g * 8) = v;
}

// ---------------------------------------------------------------------------
// bf16 MFMA GEMM: C[m][n] = sum_k A[m][k] * W[n][k] (+bias[n])
// BM=128 BN=64 BK=64, 512 threads (8 waves). Verified rounds 3-4.
// ---------------------------------------------------------------------------
template<bool ASRC_BF16, bool OUT_BF16>
__global__ __launch_bounds__(512)
void gemm_mfma(const void* __restrict__ Asrc, int lda,
               const unsigned short* __restrict__ bpack, int nks_total,
               const float* __restrict__ bias, void* __restrict__ Cdst, int ldc,
               int K)
{
    const int tid = threadIdx.x;
    const int w = tid >> 6, lane = tid & 63;
    const int l15 = lane & 15, kg = (lane >> 4) & 3;
    const int bm = blockIdx.x * 128, bn = blockIdx.y * 64;

    __shared__ unsigned short As[2][128 * 64];

    const int srow = tid >> 2;           // 0..127
    const int scol = (tid & 3) * 16;     // 0,16,32,48
    const int nkt = K / 64;

    f32x4 acc[4];
#pragma unroll
    for (int nt = 0; nt < 4; nt++) acc[nt] = 0.f;

    const int wb0 = srow * 128 + ((scol * 2) ^ ((srow & 7) << 4));
    const int wb1 = srow * 128 + ((scol * 2 + 16) ^ ((srow & 7) << 4));

#define STAGE(kt, buf) do {                                                         \
        const int gk = (kt) * 64 + scol;                                            \
        unsigned short tmp[16];                                                     \
        if (ASRC_BF16) {                                                            \
            const unsigned short* A = (const unsigned short*)Asrc;                  \
            *(uint4*)(tmp)     = *(const uint4*)(A + (size_t)(bm + srow) * lda + gk);      \
            *(uint4*)(tmp + 8) = *(const uint4*)(A + (size_t)(bm + srow) * lda + gk + 8);  \
        } else {                                                                    \
            const float* A = (const float*)Asrc;                                    \
            const float4 a0 = *(const float4*)(A + (size_t)(bm + srow) * lda + gk);       \
            const float4 a1 = *(const float4*)(A + (size_t)(bm + srow) * lda + gk + 4);   \
            const float4 a2 = *(const float4*)(A + (size_t)(bm + srow) * lda + gk + 8);   \
            const float4 a3 = *(const float4*)(A + (size_t)(bm + srow) * lda + gk + 12);  \
            tmp[0] = f2bf(a0.x);  tmp[1] = f2bf(a0.y);  tmp[2] = f2bf(a0.z);  tmp[3] = f2bf(a0.w);   \
            tmp[4] = f2bf(a1.x);  tmp[5] = f2bf(a1.y);  tmp[6] = f2bf(a1.z);  tmp[7] = f2bf(a1.w);   \
            tmp[8] = f2bf(a2.x);  tmp[9] = f2bf(a2.y);  tmp[10] = f2bf(a2.z); tmp[11] = f2bf(a2.w);  \
            tmp[12] = f2bf(a3.x); tmp[13] = f2bf(a3.y); tmp[14] = f2bf(a3.z); tmp[15] = f2bf(a3.w);  \
        }                                                                           \
        *(uint4*)((char*)As[buf] + wb0) = *(uint4*)tmp;                             \
        *(uint4*)((char*)As[buf] + wb1) = *(uint4*)(tmp + 8);                       \
    } while (0)

    STAGE(0, 0);
    __syncthreads();

    for (int kt = 0; kt < nkt; ++kt) {
        if (kt + 1 < nkt) STAGE(kt + 1, (kt + 1) & 1);
        const unsigned short* buf = As[kt & 1];
        const int row = w * 16 + l15;
#pragma unroll
        for (int ks = 0; ks < 2; ++ks) {
            const int bo = row * 128 + (((ks * 64) + kg * 16) ^ ((row & 7) << 4));
            const bf16x8 a = *(const bf16x8*)((const char*)buf + bo);
#pragma unroll
            for (int nt = 0; nt < 4; ++nt) {
                const int T = blockIdx.y * 4 + nt;
                const bf16x8 b = *(const bf16x8*)(bpack + (((size_t)T * nks_total + (kt * 2 + ks)) * 64 + lane) * 8);
                acc[nt] = __builtin_amdgcn_mfma_f32_16x16x32_bf16(a, b, acc[nt], 0, 0, 0);
            }
        }
        __syncthreads();
    }
#undef STAGE

#pragma unroll
    for (int nt = 0; nt < 4; ++nt) {
        const int n = bn + nt * 16 + l15;
        const float bv = bias ? bias[n] : 0.f;
#pragma unroll
        for (int rr = 0; rr < 4; ++rr) {
            const int m = bm + w * 16 + kg * 4 + rr;
            const float v = acc[nt][rr] + bv;
            if (OUT_BF16) ((unsigned short*)Cdst)[(size_t)m * ldc + n] = f2bf(v);
            else          ((float*)Cdst)[(size_t)m * ldc + n] = v;
        }
    }
}

// ---------------------------------------------------------------------------
// xg producer (verified round 4): xg[(seq-seq0)*16+p][g*256+u] =
//   bf16( latg[seq][g*256+u] + premixB[byte(seq,p)][g*256+u] )
// premix g-slice staged in LDS; all global traffic streaming/coalesced.
// ---------------------------------------------------------------------------
__global__ __launch_bounds__(512)
void xg_producer(const int* __restrict__ bytes,          // [NSEQ*16]
                 const float* __restrict__ latg,         // [NSEQ][768]
                 const unsigned short* __restrict__ premixB, // [256][768] bf16
                 unsigned short* __restrict__ xg,        // [SPC*16][768] bf16
                 int seq0)
{
    __shared__ unsigned short PM[256 * 256];   // 128 KB g-slice
    __shared__ int BY[32 * 16];

    const int tid = threadIdx.x;
    const int g = blockIdx.y;
    const int sblk = seq0 + blockIdx.x * 32;

#pragma unroll
    for (int j = 0; j < 16; ++j) {
        const int idx = j * 512 + tid;       // uint4 index (8 bf16)
        const int flat = idx * 8;
        const int bv = flat >> 8, u = flat & 255;
        *(uint4*)(PM + flat) = *(const uint4*)(premixB + (size_t)bv * 768 + g * 256 + u);
    }
    BY[tid & 511] = bytes[(size_t)sblk * PATCHL + (tid & 511)];
    __syncthreads();

    const int ug = (tid & 63) * 4;       // 4 consecutive gate units
    const int sg = tid >> 6;             // 0..7: seq sub-slot

    for (int si = 0; si < 4; ++si) {
        const int sl = si * 8 + sg;      // 0..31
        const int seq = sblk + sl;
        const float4 lat = *(const float4*)(latg + (size_t)seq * 768 + g * 256 + ug);
        unsigned short* dst = xg + ((size_t)(seq - seq0) * PATCHL) * 768 + g * 256 + ug;
#pragma unroll
        for (int p = 0; p < PATCHL; ++p) {
            const int bv = p ? BY[sl * PATCHL + p - 1] : 0;
            const ushort4 pm = *(const ushort4*)(PM + bv * 256 + ug);
            ushort4 o;
            o.x = f2bf(lat.x + bf2f(pm.x));
            o.y = f2bf(lat.y + bf2f(pm.y));
            o.z = f2bf(lat.z + bf2f(pm.z));
            o.w = f2bf(lat.w + bf2f(pm.w));
            *(ushort4*)(dst + (size_t)p * 768) = o;
        }
    }
}

// ---------------------------------------------------------------------------
// GRU recurrence scan (no head). 32 seqs/block, 512 threads.
// Per step: stage xg slice to LDS (coalesced) -> barrier -> gate MFMA from
// H(LDS, swizzled) x W_hh pack (L2) -> gate math from XG(LDS) -> write Hnxt
// -> barrier -> coalesced copy Hnxt -> h_hist (bf16).
// ---------------------------------------------------------------------------
#define XGS 776   // padded row stride (shorts): 1552 B, breaks bank aliasing
__global__ __launch_bounds__(512, 4)
void gru_scan(const unsigned short* __restrict__ xg,     // [SPC*16][768]
              const unsigned short* __restrict__ wpack,  // 48 gate tiles
              const float* __restrict__ b_hh,            // [768]
              unsigned short* __restrict__ hh)           // [SPC*16][256] bf16
{
    const int tid  = threadIdx.x;
    const int w    = tid >> 6;
    const int lane = tid & 63;
    const int l15  = lane & 15;
    const int kg   = (lane >> 4) & 3;
    const int s0l  = blockIdx.x * 32;

    __shared__ unsigned short XG[32 * XGS];   // ~48.5 KB
    __shared__ unsigned short H0[32 * 256];   // 16 KB
    __shared__ unsigned short H1[32 * 256];

    float bhr[2], bhz[2], bhn[2];
#pragma unroll
    for (int nt = 0; nt < 2; nt++) {
        const int u = w * 32 + nt * 16 + l15;
        bhr[nt] = b_hh[u]; bhz[nt] = b_hh[256 + u]; bhn[nt] = b_hh[512 + u];
    }

    float hreg[2][2][4];
#pragma unroll
    for (int mt = 0; mt < 2; mt++)
#pragma unroll
        for (int nt = 0; nt < 2; nt++)
#pragma unroll
            for (int rr = 0; rr < 4; rr++) hreg[mt][nt][rr] = 0.f;

    unsigned short* Hcur = H0;
    unsigned short* Hnxt = H1;

    for (int p = 0; p < PATCHL; ++p) {
        // ---- stage this step's gate inputs: 32 rows x 1536 B, coalesced ----
#pragma unroll
        for (int j = 0; j < 6; ++j) {
            const int idx = j * 512 + tid;          // uint4 index; 96 per row
            const int row = idx / 96, col = idx % 96;
            *(uint4*)(XG + row * XGS + col * 8) =
                *(const uint4*)(xg + ((size_t)(s0l + row) * PATCHL + p) * 768 + col * 8);
        }
        __syncthreads();

        // ---------------- recurrence: hg = h_prev @ W_hh^T ----------------
        f32x4 accr[2][2], accz[2][2], accn[2][2];
#pragma unroll
        for (int mt = 0; mt < 2; mt++)
#pragma unroll
            for (int nt = 0; nt < 2; nt++) {
                accr[mt][nt] = 0.f; accz[mt][nt] = 0.f; accn[mt][nt] = 0.f;
            }
        if (p != 0) {
#pragma unroll
            for (int ks = 0; ks < 8; ++ks) {
                bf16x8 a[2];
#pragma unroll
                for (int mt = 0; mt < 2; mt++) {
                    const int s = mt * 16 + l15;
                    const int off = (ks * 64 + kg * 16) ^ ((s & 7) << 4);
                    a[mt] = *(const bf16x8*)(Hcur + s * 256 + (off >> 1));
                }
#pragma unroll
                for (int nt = 0; nt < 2; nt++) {
                    const int tb = w * 2 + nt;
                    const bf16x8 br = *(const bf16x8*)(wpack + (((size_t)(tb)      * 8 + ks) * 64 + lane) * 8);
                    const bf16x8 bz = *(const bf16x8*)(wpack + (((size_t)(16 + tb) * 8 + ks) * 64 + lane) * 8);
                    const bf16x8 bn = *(const bf16x8*)(wpack + (((size_t)(32 + tb) * 8 + ks) * 64 + lane) * 8);
#pragma unroll
                    for (int mt = 0; mt < 2; mt++) {
                        accr[mt][nt] = __builtin_amdgcn_mfma_f32_16x16x32_bf16(a[mt], br, accr[mt][nt], 0, 0, 0);
                        accz[mt][nt] = __builtin_amdgcn_mfma_f32_16x16x32_bf16(a[mt], bz, accz[mt][nt], 0, 0, 0);
                        accn[mt][nt] = __builtin_amdgcn_mfma_f32_16x16x32_bf16(a[mt], bn, accn[mt][nt], 0, 0, 0);
                    }
                }
            }
        }
        // ---------------- gates + state update (fp32) ----------------
#pragma unroll
        for (int mt = 0; mt < 2; mt++)
#pragma unroll
            for (int nt = 0; nt < 2; nt++) {
                const int u = w * 32 + nt * 16 + l15;
#pragma unroll
                for (int rr = 0; rr < 4; rr++) {
                    const int sl = mt * 16 + kg * 4 + rr;
                    const float xr = bf2f(XG[sl * XGS + u]);
                    const float xz = bf2f(XG[sl * XGS + 256 + u]);
                    const float xn = bf2f(XG[sl * XGS + 512 + u]);
                    const float r = sigf(xr + accr[mt][nt][rr] + bhr[nt]);
                    const float z = sigf(xz + accz[mt][nt][rr] + bhz[nt]);
                    const float n = tanhf_(xn + r * (accn[mt][nt][rr] + bhn[nt]));
                    const float hn_ = (1.f - z) * n + z * hreg[mt][nt][rr];
                    hreg[mt][nt][rr] = hn_;
                    const int bo = (2 * u) ^ ((sl & 7) << 4);
                    Hnxt[sl * 256 + (bo >> 1)] = f2bf(hn_);
                }
            }
        __syncthreads();

        // ---- coalesced h_hist write: wave w copies rows w*4..w*4+3 ----
#pragma unroll
        for (int rj = 0; rj < 4; ++rj) {
            const int row = w * 4 + rj;
            const int boff = (lane * 8) ^ ((row & 7) << 4);   // un-swizzle
            const ushort4 v = *(const ushort4*)((const char*)(Hnxt + row * 256) + boff);
            *(ushort4*)(hh + ((size_t)(s0l + row) * PATCHL + p) * 256 + lane * 4) = v;
        }

        unsigned short* t_ = Hcur; Hcur = Hnxt; Hnxt = t_;
    }
}

// ---------------------------------------------------------------------------
extern "C" void kernel_launch(void* const* d_in, const int* in_sizes, int n_in,
                              void* d_out, int out_size, void* d_ws, size_t ws_size,
                              hipStream_t stream)
{
    const float* latents = (const float*)d_in[0];   // [8192][1024]
    const int*   tb      = (const int*)d_in[1];     // [8192*16]
    const float* W_proj  = (const float*)d_in[2];   // [256][1024]
    const float* b_proj  = (const float*)d_in[3];   // [256]
    const float* emb     = (const float*)d_in[4];   // [256][256]
    const float* W_ih    = (const float*)d_in[5];   // [768][512]
    const float* W_hh    = (const float*)d_in[6];   // [768][256]
    const float* b_ih    = (const float*)d_in[7];   // [768]
    const float* b_hh    = (const float*)d_in[8];   // [768]
    const float* W_head  = (const float*)d_in[9];   // [256][256]
    const float* b_head  = (const float*)d_in[10];  // [256]
    float* out = (float*)d_out;

    // ---- workspace layout (bytes) ----
    char* w = (char*)d_ws;
    float* latg = (float*)w;                               w += (size_t)NSEQ * 768 * 4;     // 25.2 MB
    unsigned short* ctxb    = (unsigned short*)w;          w += (size_t)NSEQ * HIDN * 2;    // 4.2 MB
    unsigned short* premixB = (unsigned short*)w;          w += 256 * 768 * 2;
    unsigned short* bpack1  = (unsigned short*)w;          w += 16 * 32 * 64 * 8 * 2;
    unsigned short* bpack2  = (unsigned short*)w;          w += 48 * 8 * 64 * 8 * 2;
    unsigned short* bpack3  = (unsigned short*)w;          w += 48 * 8 * 64 * 8 * 2;
    unsigned short* wpackG  = (unsigned short*)w;          w += 48 * 8 * 64 * 8 * 2;        // gates only
    unsigned short* bpackH  = (unsigned short*)w;          w += 16 * 8 * 64 * 8 * 2;        // head
    unsigned short* xg_c    = (unsigned short*)w;
    const size_t fixed_bytes = (size_t)(w - (char*)d_ws);
    const size_t chunk_full  = (size_t)NSEQ * PATCHL * (768 + 256) * 2;   // xg + hh = 268 MB

    int nch = 1;
    while (nch < 16 && fixed_bytes + chunk_full / nch > ws_size) nch <<= 1;
    const int SPC = NSEQ / nch;                    // seqs per chunk
    unsigned short* hh_c = xg_c + (size_t)SPC * PATCHL * 768;

    // ---- weight packs (fragment-ordered bf16) ----
    hipLaunchKernelGGL(pack_frag, dim3(128), dim3(256), 0, stream, W_proj, 1024, 0, 32, bpack1);
    hipLaunchKernelGGL(pack_frag, dim3(96),  dim3(256), 0, stream, W_ih,   512, 256, 8, bpack2);
    hipLaunchKernelGGL(pack_frag, dim3(96),  dim3(256), 0, stream, W_ih,   512, 0,   8, bpack3);
    hipLaunchKernelGGL(pack_frag, dim3(96),  dim3(256), 0, stream, W_hh,   256, 0,   8, wpackG);
    hipLaunchKernelGGL(pack_frag, dim3(32),  dim3(256), 0, stream, W_head, 256, 0,   8, bpackH);

    // premixB(bf16) = emb @ W_ih[:,0:256]^T        [256][768]
    hipLaunchKernelGGL((gemm_mfma<false, true>), dim3(2, 12), dim3(512), 0, stream,
                       emb, 256, bpack3, 8, nullptr, premixB, 768, 256);
    // ctx(bf16) = latents @ W_proj^T + b_proj      [8192][256]
    hipLaunchKernelGGL((gemm_mfma<false, true>), dim3(NSEQ / 128, 4), dim3(512), 0, stream,
                       latents, 1024, bpack1, 32, b_proj, ctxb, 256, 1024);
    // latg(f32) = ctx @ W_ih[:,256:512]^T + b_ih   [8192][768]
    hipLaunchKernelGGL((gemm_mfma<true, false>), dim3(NSEQ / 128, 12), dim3(512), 0, stream,
                       ctxb, 256, bpack2, 8, b_ih, latg, 768, 256);

    // ---- per-chunk: producer -> scan -> head GEMM (stream-ordered) ----
    for (int c = 0; c < nch; ++c) {
        const int seq0 = c * SPC;
        hipLaunchKernelGGL(xg_producer, dim3(SPC / 32, 3), dim3(512), 0, stream,
                           tb, latg, premixB, xg_c, seq0);
        hipLaunchKernelGGL(gru_scan, dim3(SPC / 32), dim3(512), 0, stream,
                           xg_c, wpackG, b_hh, hh_c);
        // logits = h_hist @ W_head^T + b_head    [SPC*16][256]
        hipLaunchKernelGGL((gemm_mfma<true, false>), dim3(SPC * PATCHL / 128, 4), dim3(512), 0, stream,
                           hh_c, 256, bpackH, 8, b_head,
                           out + (size_t)seq0 * PATCHL * VOCABN, 256, 256);
    }
}